// Round 1
// baseline (275.499 us; speedup 1.0000x reference)
//
#include <hip/hip_runtime.h>
#include <math.h>

// Problem constants (fixed by reference: B=32,T=1024,D=256,K=1024)
#define N_ROWS 32768
#define DIM    256
#define KCODES 1024
#define DELTA  1.5e-4f   // rescue margin >> (approx err ~1e-5 + fp32 quant band ~6e-5)

typedef float f32x4 __attribute__((ext_vector_type(4)));
typedef short s16x8 __attribute__((ext_vector_type(8)));

__device__ inline unsigned short bf_rne(float f) {
    unsigned u = __float_as_uint(f);
    return (unsigned short)((u + 0x7FFFu + ((u >> 16) & 1u)) >> 16);
}
__device__ inline float bf_to_f(unsigned short h) {
    return __uint_as_float(((unsigned)h) << 16);
}

// lex insert (v,ix) into ascending top-4 (ties -> lower index first)
__device__ inline void ins4(float v, int ix, float (&tv)[4], int (&ti)[4]) {
    if (v < tv[3] || (v == tv[3] && ix < ti[3])) {
        if (v < tv[2] || (v == tv[2] && ix < ti[2])) {
            tv[3] = tv[2]; ti[3] = ti[2];
            if (v < tv[1] || (v == tv[1] && ix < ti[1])) {
                tv[2] = tv[1]; ti[2] = ti[1];
                if (v < tv[0] || (v == tv[0] && ix < ti[0])) {
                    tv[1] = tv[0]; ti[1] = ti[0]; tv[0] = v; ti[0] = ix;
                } else { tv[1] = v; ti[1] = ix; }
            } else { tv[2] = v; ti[2] = ix; }
        } else { tv[3] = v; ti[3] = ix; }
    }
}

// async global->LDS, 16B per lane. LDS dest = wave-uniform base + lane*16 (HW rule).
__device__ __forceinline__ void gl_lds16(const void* gp, void* lp) {
    __builtin_amdgcn_global_load_lds(
        (__attribute__((address_space(1))) void*)(void*)gp,
        (__attribute__((address_space(3))) void*)lp, 16, 0, 0);
}

// ---------------------------------------------------------------------------
// numpy pairwise sum-of-squares (n=256), proven R2. One wave per row.
__global__ __launch_bounds__(256) void rowsum_sq_kernel(const float* __restrict__ src,
                                                        float* __restrict__ dst,
                                                        int nrows) {
    __shared__ float sq[4][260];
    const int wave = threadIdx.x >> 6;
    const int lane = threadIdx.x & 63;
    const int row  = blockIdx.x * 4 + wave;
    if (row >= nrows) return;
    const float4* rp = (const float4*)(src + (size_t)row * DIM);
    float4 v = rp[lane];
    sq[wave][lane * 4 + 0] = v.x * v.x;
    sq[wave][lane * 4 + 1] = v.y * v.y;
    sq[wave][lane * 4 + 2] = v.z * v.z;
    sq[wave][lane * 4 + 3] = v.w * v.w;
    if (lane < 8) {
#pragma clang fp contract(off)
        const int j = lane;
        float rA = sq[wave][j];
#pragma unroll
        for (int m = 1; m < 16; ++m) rA += sq[wave][8 * m + j];
        float rB = sq[wave][128 + j];
#pragma unroll
        for (int m = 1; m < 16; ++m) rB += sq[wave][128 + 8 * m + j];
        rA = rA + __shfl_xor(rA, 1, 64); rA = rA + __shfl_xor(rA, 2, 64);
        rA = rA + __shfl_xor(rA, 4, 64);
        rB = rB + __shfl_xor(rB, 1, 64); rB = rB + __shfl_xor(rB, 2, 64);
        rB = rB + __shfl_xor(rB, 4, 64);
        if (j == 0) dst[row] = rA + rB;
    }
}

// ---------------------------------------------------------------------------
// E prep: e2 (numpy pairwise, proven) + bf16 hi/lo split of E.
__global__ __launch_bounds__(256) void prep_e_kernel(const float* __restrict__ E,
                                                     float* __restrict__ e2,
                                                     unsigned short* __restrict__ Eh,
                                                     unsigned short* __restrict__ El) {
    __shared__ float sq[4][260];
    const int wave = threadIdx.x >> 6;
    const int lane = threadIdx.x & 63;
    const int row  = blockIdx.x * 4 + wave;
    const float4* rp = (const float4*)(E + (size_t)row * DIM);
    float4 v = rp[lane];
    sq[wave][lane * 4 + 0] = v.x * v.x;
    sq[wave][lane * 4 + 1] = v.y * v.y;
    sq[wave][lane * 4 + 2] = v.z * v.z;
    sq[wave][lane * 4 + 3] = v.w * v.w;
    float fs[4] = {v.x, v.y, v.z, v.w};
    ushort4 hv, lv;
    unsigned short* hp = (unsigned short*)&hv;
    unsigned short* lp = (unsigned short*)&lv;
#pragma unroll
    for (int j = 0; j < 4; ++j) {
        unsigned short h = bf_rne(fs[j]);
        hp[j] = h;
        lp[j] = bf_rne(fs[j] - bf_to_f(h));
    }
    *(ushort4*)(Eh + (size_t)row * DIM + lane * 4) = hv;
    *(ushort4*)(El + (size_t)row * DIM + lane * 4) = lv;
    if (lane < 8) {
#pragma clang fp contract(off)
        const int j = lane;
        float rA = sq[wave][j];
#pragma unroll
        for (int m = 1; m < 16; ++m) rA += sq[wave][8 * m + j];
        float rB = sq[wave][128 + j];
#pragma unroll
        for (int m = 1; m < 16; ++m) rB += sq[wave][128 + 8 * m + j];
        rA = rA + __shfl_xor(rA, 1, 64); rA = rA + __shfl_xor(rA, 2, 64);
        rA = rA + __shfl_xor(rA, 4, 64);
        rB = rB + __shfl_xor(rB, 1, 64); rB = rB + __shfl_xor(rB, 2, 64);
        rB = rB + __shfl_xor(rB, 4, 64);
        if (j == 0) e2[row] = rA + rB;
    }
}

// ---------------------------------------------------------------------------
// MFMA screening, operand-swapped: A = codes (LDS), B = x-rows (registers).
// Wave owns 32 x-rows (2 tiles of 16); each lane tracks top-4 for ONE x-row per
// tile (C/D col = lane&15 = x-row, row = quad*4+reg = code). 6 MFMA per 2
// ds_read_b128 (48 FLOP/LDS-byte -> MFMA-bound). Staging: async global_load_lds
// (LDS slot (g,l) = base g*1024B + lane*16B, exactly the HW write pattern),
// double-buffered, ONE barrier per 64-code chunk.
// Scores bit-identical to prior kernel: same products, same shape/k-order,
// same c0+c1+c2 association, same e2-2d formula, exact-lex top-4 merge.
__global__ __launch_bounds__(256, 1) void vq_mfma_kernel(const float* __restrict__ X,
                                                         const unsigned short* __restrict__ Eh,
                                                         const unsigned short* __restrict__ El,
                                                         const float* __restrict__ e2g,
                                                         float* __restrict__ topv,
                                                         int* __restrict__ topi) {
    __shared__ __align__(16) short bh_lds[2][16384];  // 2 x 32 KB code-hi chunks
    __shared__ __align__(16) short bl_lds[2][16384];  // 2 x 32 KB code-lo chunks
    __shared__ float e2_lds[KCODES];                  // 4 KB

    const int tid  = threadIdx.x;
    const int w    = tid >> 6;
    const int l    = tid & 63;
    const int c16  = l & 15;
    const int quad = l >> 4;
    const int row0 = blockIdx.x * 128;

    // e2 -> LDS once (drained by first barrier)
    *(float4*)&e2_lds[tid * 4] = *(const float4*)&e2g[tid * 4];

    // ---- X fragments (B-operand): 2 tiles x 16 rows, hi+lo, K=256 ----
    s16x8 xh[2][8], xl[2][8];
#pragma unroll
    for (int t = 0; t < 2; ++t) {
        const float* xrow = X + (size_t)(row0 + w * 32 + t * 16 + c16) * DIM + quad * 8;
#pragma unroll
        for (int ks = 0; ks < 8; ++ks) {
            float4 f0 = *(const float4*)(xrow + ks * 32);
            float4 f1 = *(const float4*)(xrow + ks * 32 + 4);
            float fs[8] = {f0.x, f0.y, f0.z, f0.w, f1.x, f1.y, f1.z, f1.w};
#pragma unroll
            for (int j = 0; j < 8; ++j) {
                unsigned short h = bf_rne(fs[j]);
                xh[t][ks][j] = (short)h;
                xl[t][ks][j] = (short)bf_rne(fs[j] - bf_to_f(h));
            }
        }
    }

    float tva[4], tvb[4];
    int   tia[4], tib[4];
#pragma unroll
    for (int s = 0; s < 4; ++s) {
        tva[s] = INFINITY; tvb[s] = INFINITY;
        tia[s] = 0x7fffffff; tib[s] = 0x7fffffff;
    }

    // stage codes [cb, cb+64) into buffer bsel: 32 groups (nt,ks), wave does 8
    auto stage = [&](int bsel, int cb) {
#pragma unroll
        for (int gg = 0; gg < 8; ++gg) {
            const int g  = w + gg * 4;              // wave-uniform
            const int nt = g >> 3, ks = g & 7;
            const size_t eo = (size_t)(cb + nt * 16 + c16) * DIM + ks * 32 + quad * 8;
            gl_lds16(Eh + eo, &bh_lds[bsel][g * 512]);
            gl_lds16(El + eo, &bl_lds[bsel][g * 512]);
        }
    };

    stage(0, 0);

    for (int c = 0; c < 16; ++c) {
        __syncthreads();                 // drains vmcnt: buf[c&1] ready; prev reads done
        if (c < 15) stage((c + 1) & 1, (c + 1) * 64);   // prefetch under this chunk's MFMAs
        const int bsel = c & 1;
#pragma unroll
        for (int nt = 0; nt < 4; ++nt) {
            f32x4 c0a = {0.f, 0.f, 0.f, 0.f};
            f32x4 c1a = c0a, c2a = c0a, c0b = c0a, c1b = c0a, c2b = c0a;
#pragma unroll
            for (int ks = 0; ks < 8; ++ks) {
                const int off = ((nt * 8 + ks) * 64 + l) * 8;
                s16x8 ch = *(const s16x8*)&bh_lds[bsel][off];
                s16x8 cl = *(const s16x8*)&bl_lds[bsel][off];
                c0a = __builtin_amdgcn_mfma_f32_16x16x32_bf16(ch, xh[0][ks], c0a, 0, 0, 0);
                c0b = __builtin_amdgcn_mfma_f32_16x16x32_bf16(ch, xh[1][ks], c0b, 0, 0, 0);
                c1a = __builtin_amdgcn_mfma_f32_16x16x32_bf16(cl, xh[0][ks], c1a, 0, 0, 0);
                c1b = __builtin_amdgcn_mfma_f32_16x16x32_bf16(cl, xh[1][ks], c1b, 0, 0, 0);
                c2a = __builtin_amdgcn_mfma_f32_16x16x32_bf16(ch, xl[0][ks], c2a, 0, 0, 0);
                c2b = __builtin_amdgcn_mfma_f32_16x16x32_bf16(ch, xl[1][ks], c2b, 0, 0, 0);
            }
#pragma unroll
            for (int r = 0; r < 4; ++r) {
                const int code = c * 64 + nt * 16 + quad * 4 + r;
                const float e2v = e2_lds[code];
                float da = c0a[r] + c1a[r] + c2a[r];
                float db = c0b[r] + c1b[r] + c2b[r];
                ins4(e2v - 2.0f * da, code, tva, tia);
                ins4(e2v - 2.0f * db, code, tvb, tib);
            }
        }
    }

    // merge top-4 across the 4 quads holding the same x-row (lanes l, l^16, l^32)
#pragma unroll
    for (int st = 16; st <= 32; st <<= 1) {
        float ov[4]; int oi[4];
#pragma unroll
        for (int s = 0; s < 4; ++s) {
            ov[s] = __shfl_xor(tva[s], st, 64);
            oi[s] = __shfl_xor(tia[s], st, 64);
        }
#pragma unroll
        for (int s = 0; s < 4; ++s) ins4(ov[s], oi[s], tva, tia);
#pragma unroll
        for (int s = 0; s < 4; ++s) {
            ov[s] = __shfl_xor(tvb[s], st, 64);
            oi[s] = __shfl_xor(tib[s], st, 64);
        }
#pragma unroll
        for (int s = 0; s < 4; ++s) ins4(ov[s], oi[s], tvb, tib);
    }
    if (quad == 0) {
        const int ga = row0 + w * 32 + c16;   // tile 0 row
        const int gb = ga + 16;               // tile 1 row
#pragma unroll
        for (int s = 0; s < 4; ++s) {
            topv[ga * 4 + s] = tva[s]; topi[ga * 4 + s] = tia[s];
            topv[gb * 4 + s] = tvb[s]; topi[gb * 4 + s] = tib[s];
        }
    }
}

// ---------------------------------------------------------------------------
// Decide: fast path idx=ti[0] when unambiguous; else exact fp32 rescore of all
// candidates within DELTA using the R2-proven numpy-rounded score + index ties.
__global__ __launch_bounds__(256) void decide_kernel(const float* __restrict__ X,
                                                     const float* __restrict__ E,
                                                     const float* __restrict__ e2g,
                                                     const float* __restrict__ x2g,
                                                     const float* __restrict__ topv,
                                                     const int* __restrict__ topi,
                                                     int* __restrict__ idxw,
                                                     float* __restrict__ out2) {
    const int r = blockIdx.x * 256 + threadIdx.x;
    float tv[4]; int ti[4];
#pragma unroll
    for (int s = 0; s < 4; ++s) { tv[s] = topv[r * 4 + s]; ti[s] = topi[r * 4 + s]; }

    int best = ti[0];
    if (!(tv[1] > tv[0] + DELTA)) {
        const float* xr = X + (size_t)r * DIM;
        const float x2v = x2g[r];
        float bq = INFINITY; int bi = 0x7fffffff;
        for (int cnd = 0; cnd < 4; ++cnd) {
            if (tv[cnd] <= tv[0] + DELTA) {
                const int k = ti[cnd];
                const float* er = E + (size_t)k * DIM;
                float dot = 0.f;
                for (int d = 0; d < DIM; d += 4) {   // sequential fp32 chain (BLAS order)
                    float4 xv = *(const float4*)(xr + d);
                    float4 ev = *(const float4*)(er + d);
                    dot = fmaf(xv.x, ev.x, dot);
                    dot = fmaf(xv.y, ev.y, dot);
                    dot = fmaf(xv.z, ev.z, dot);
                    dot = fmaf(xv.w, ev.w, dot);
                }
                float t1 = e2g[k] - 2.0f * dot;   // numpy elementwise rounding
                float q  = t1 + x2v;
                if (q < bq || (q == bq && k < bi)) { bq = q; bi = k; }
            }
        }
        best = bi;
    }
    idxw[r] = best;
    out2[r] = (float)best;
}

// ---------------------------------------------------------------------------
// Gather epilogue (proven pattern): 64 rows/block, coalesced float4 writes.
__global__ __launch_bounds__(256) void gather_kernel(const float* __restrict__ E,
                                                     const int* __restrict__ idxw,
                                                     float* __restrict__ out0,
                                                     float* __restrict__ out1) {
    const int tid  = threadIdx.x;
    const int row0 = blockIdx.x * 64;
#pragma unroll
    for (int it = 0; it < 16; ++it) {
        int f = tid + it * 256;
        int rr = f >> 6;
        int p  = f & 63;
        int ix = idxw[row0 + rr];
        float4 v = *(const float4*)(E + (size_t)ix * DIM + p * 4);
        size_t o = (size_t)(row0 + rr) * DIM + (size_t)p * 4;
        *(float4*)(out0 + o) = v;
        *(float4*)(out1 + o) = v;
    }
}

// ---------------------------------------------------------------------------
extern "C" void kernel_launch(void* const* d_in, const int* in_sizes, int n_in,
                              void* d_out, int out_size, void* d_ws, size_t ws_size,
                              hipStream_t stream) {
    const float* X = (const float*)d_in[0];
    const float* E = (const float*)d_in[1];

    // ws layout (all 16B-aligned): ~2.4 MB total
    float* e2 = (float*)d_ws;                              // 1024 f
    float* x2 = e2 + KCODES;                               // 32768 f
    unsigned short* Eh = (unsigned short*)(x2 + N_ROWS);   // 262144 us
    unsigned short* El = Eh + KCODES * DIM;                // 262144 us
    float* topv = (float*)(El + KCODES * DIM);             // 131072 f
    int*   topi = (int*)(topv + N_ROWS * 4);               // 131072 i
    int*   idxw = topi + N_ROWS * 4;                       // 32768 i

    float* out0 = (float*)d_out;
    float* out1 = out0 + (size_t)N_ROWS * DIM;
    float* out2 = out1 + (size_t)N_ROWS * DIM;

    prep_e_kernel   <<<dim3(KCODES / 4), dim3(256), 0, stream>>>(E, e2, Eh, El);
    rowsum_sq_kernel<<<dim3(N_ROWS / 4), dim3(256), 0, stream>>>(X, x2, N_ROWS);
    vq_mfma_kernel  <<<dim3(N_ROWS / 128), dim3(256), 0, stream>>>(X, Eh, El, e2,
                                                                   topv, topi);
    decide_kernel   <<<dim3(N_ROWS / 256), dim3(256), 0, stream>>>(X, E, e2, x2,
                                                                   topv, topi,
                                                                   idxw, out2);
    gather_kernel   <<<dim3(N_ROWS / 64), dim3(256), 0, stream>>>(E, idxw,
                                                                  out0, out1);
}

// Round 2
// 233.255 us; speedup vs baseline: 1.1811x; 1.1811x over previous
//
#include <hip/hip_runtime.h>
#include <math.h>

// Problem constants (fixed by reference: B=32,T=1024,D=256,K=1024)
#define N_ROWS 32768
#define DIM    256
#define KCODES 1024
#define DELTA  1.5e-4f   // rescue margin >> (approx err ~1e-5 + fp32 quant band ~6e-5)

typedef float f32x4 __attribute__((ext_vector_type(4)));
typedef short s16x8 __attribute__((ext_vector_type(8)));

__device__ inline unsigned short bf_rne(float f) {
    unsigned u = __float_as_uint(f);
    return (unsigned short)((u + 0x7FFFu + ((u >> 16) & 1u)) >> 16);
}
__device__ inline float bf_to_f(unsigned short h) {
    return __uint_as_float(((unsigned)h) << 16);
}

// lex insert (v,ix) into ascending top-4 (ties -> lower index first)
__device__ inline void ins4(float v, int ix, float (&tv)[4], int (&ti)[4]) {
    if (v < tv[3] || (v == tv[3] && ix < ti[3])) {
        if (v < tv[2] || (v == tv[2] && ix < ti[2])) {
            tv[3] = tv[2]; ti[3] = ti[2];
            if (v < tv[1] || (v == tv[1] && ix < ti[1])) {
                tv[2] = tv[1]; ti[2] = ti[1];
                if (v < tv[0] || (v == tv[0] && ix < ti[0])) {
                    tv[1] = tv[0]; ti[1] = ti[0]; tv[0] = v; ti[0] = ix;
                } else { tv[1] = v; ti[1] = ix; }
            } else { tv[2] = v; ti[2] = ix; }
        } else { tv[3] = v; ti[3] = ix; }
    }
}

// async global->LDS, 16B per lane. LDS dest = wave-uniform base + lane*16 (HW rule).
__device__ __forceinline__ void gl_lds16(const void* gp, void* lp) {
    __builtin_amdgcn_global_load_lds(
        (__attribute__((address_space(1))) void*)(void*)gp,
        (__attribute__((address_space(3))) void*)lp, 16, 0, 0);
}

// ---------------------------------------------------------------------------
// Fused prep: blocks [0,256) do E prep (e2 pairwise + bf16 hi/lo split);
// blocks [256, 256+8192) do X row sum-of-squares. Both bodies are verbatim
// copies of the R2-proven numpy-pairwise kernels.
__global__ __launch_bounds__(256) void prep_kernel(const float* __restrict__ E,
                                                   const float* __restrict__ X,
                                                   float* __restrict__ e2,
                                                   float* __restrict__ x2,
                                                   unsigned short* __restrict__ Eh,
                                                   unsigned short* __restrict__ El) {
    __shared__ float sq[4][260];
    const int wave = threadIdx.x >> 6;
    const int lane = threadIdx.x & 63;
    if (blockIdx.x < KCODES / 4) {
        const int row = blockIdx.x * 4 + wave;
        const float4* rp = (const float4*)(E + (size_t)row * DIM);
        float4 v = rp[lane];
        sq[wave][lane * 4 + 0] = v.x * v.x;
        sq[wave][lane * 4 + 1] = v.y * v.y;
        sq[wave][lane * 4 + 2] = v.z * v.z;
        sq[wave][lane * 4 + 3] = v.w * v.w;
        float fs[4] = {v.x, v.y, v.z, v.w};
        ushort4 hv, lv;
        unsigned short* hp = (unsigned short*)&hv;
        unsigned short* lp = (unsigned short*)&lv;
#pragma unroll
        for (int j = 0; j < 4; ++j) {
            unsigned short h = bf_rne(fs[j]);
            hp[j] = h;
            lp[j] = bf_rne(fs[j] - bf_to_f(h));
        }
        *(ushort4*)(Eh + (size_t)row * DIM + lane * 4) = hv;
        *(ushort4*)(El + (size_t)row * DIM + lane * 4) = lv;
        if (lane < 8) {
#pragma clang fp contract(off)
            const int j = lane;
            float rA = sq[wave][j];
#pragma unroll
            for (int m = 1; m < 16; ++m) rA += sq[wave][8 * m + j];
            float rB = sq[wave][128 + j];
#pragma unroll
            for (int m = 1; m < 16; ++m) rB += sq[wave][128 + 8 * m + j];
            rA = rA + __shfl_xor(rA, 1, 64); rA = rA + __shfl_xor(rA, 2, 64);
            rA = rA + __shfl_xor(rA, 4, 64);
            rB = rB + __shfl_xor(rB, 1, 64); rB = rB + __shfl_xor(rB, 2, 64);
            rB = rB + __shfl_xor(rB, 4, 64);
            if (j == 0) e2[row] = rA + rB;
        }
    } else {
        const int row = (blockIdx.x - KCODES / 4) * 4 + wave;
        if (row >= N_ROWS) return;
        const float4* rp = (const float4*)(X + (size_t)row * DIM);
        float4 v = rp[lane];
        sq[wave][lane * 4 + 0] = v.x * v.x;
        sq[wave][lane * 4 + 1] = v.y * v.y;
        sq[wave][lane * 4 + 2] = v.z * v.z;
        sq[wave][lane * 4 + 3] = v.w * v.w;
        if (lane < 8) {
#pragma clang fp contract(off)
            const int j = lane;
            float rA = sq[wave][j];
#pragma unroll
            for (int m = 1; m < 16; ++m) rA += sq[wave][8 * m + j];
            float rB = sq[wave][128 + j];
#pragma unroll
            for (int m = 1; m < 16; ++m) rB += sq[wave][128 + 8 * m + j];
            rA = rA + __shfl_xor(rA, 1, 64); rA = rA + __shfl_xor(rA, 2, 64);
            rA = rA + __shfl_xor(rA, 4, 64);
            rB = rB + __shfl_xor(rB, 1, 64); rB = rB + __shfl_xor(rB, 2, 64);
            rB = rB + __shfl_xor(rB, 4, 64);
            if (j == 0) x2[row] = rA + rB;
        }
    }
}

// ---------------------------------------------------------------------------
// MFMA screening, operand-swapped (A = codes from LDS, B = x-rows in regs).
// 512 threads = 8 waves = 2 waves/SIMD (the round-1 fix: occupancy was 1
// wave/SIMD -> MfmaUtil 12%). Wave w: row-pair p = w&3 (rows p*32..p*32+31,
// 2 tiles of 16), code-group grp = w>>2 (grp 0 -> nt 0,1; grp 1 -> nt 2,3 of
// each staged 64-code chunk). Each wave keeps 6 MFMA per 2 ds_read_b128
// (48 FLOP/LDS-byte). Staging layout and numerics byte-identical to round 1;
// group top-4 lists (disjoint code halves) merged exactly via LDS scratch.
__global__ __launch_bounds__(512, 2) void vq_mfma_kernel(const float* __restrict__ X,
                                                         const unsigned short* __restrict__ Eh,
                                                         const unsigned short* __restrict__ El,
                                                         const float* __restrict__ e2g,
                                                         float* __restrict__ topv,
                                                         int* __restrict__ topi) {
    __shared__ __align__(16) short bh_lds[2][16384];  // 2 x 32 KB code-hi chunks
    __shared__ __align__(16) short bl_lds[2][16384];  // 2 x 32 KB code-lo chunks
    __shared__ float e2_lds[KCODES];                  // 4 KB

    const int tid  = threadIdx.x;
    const int w    = tid >> 6;
    const int l    = tid & 63;
    const int c16  = l & 15;
    const int quad = l >> 4;
    const int p    = w & 3;    // row-pair index (rows p*32 .. p*32+31)
    const int grp  = w >> 2;   // code half: 0 -> nt 0,1 ; 1 -> nt 2,3
    const int row0 = blockIdx.x * 128;

    // e2 -> LDS once (drained by first barrier)
    if (tid < 256) *(float4*)&e2_lds[tid * 4] = *(const float4*)&e2g[tid * 4];

    // ---- X fragments (B-operand): 2 tiles x 16 rows, hi+lo, K=256 ----
    s16x8 xh[2][8], xl[2][8];
#pragma unroll
    for (int t = 0; t < 2; ++t) {
        const float* xrow = X + (size_t)(row0 + p * 32 + t * 16 + c16) * DIM + quad * 8;
#pragma unroll
        for (int ks = 0; ks < 8; ++ks) {
            float4 f0 = *(const float4*)(xrow + ks * 32);
            float4 f1 = *(const float4*)(xrow + ks * 32 + 4);
            float fs[8] = {f0.x, f0.y, f0.z, f0.w, f1.x, f1.y, f1.z, f1.w};
#pragma unroll
            for (int j = 0; j < 8; ++j) {
                unsigned short h = bf_rne(fs[j]);
                xh[t][ks][j] = (short)h;
                xl[t][ks][j] = (short)bf_rne(fs[j] - bf_to_f(h));
            }
        }
    }

    float tva[4], tvb[4];
    int   tia[4], tib[4];
#pragma unroll
    for (int s = 0; s < 4; ++s) {
        tva[s] = INFINITY; tvb[s] = INFINITY;
        tia[s] = 0x7fffffff; tib[s] = 0x7fffffff;
    }

    // stage codes [cb, cb+64): 32 granules of 1KB per array; 8 waves x 4 each
    auto stage = [&](int bsel, int cb) {
#pragma unroll
        for (int gg = 0; gg < 4; ++gg) {
            const int g  = w + gg * 8;              // wave-uniform, 0..31
            const int nt = g >> 3, ks = g & 7;
            const size_t eo = (size_t)(cb + nt * 16 + c16) * DIM + ks * 32 + quad * 8;
            gl_lds16(Eh + eo, &bh_lds[bsel][g * 512]);
            gl_lds16(El + eo, &bl_lds[bsel][g * 512]);
        }
    };

    stage(0, 0);

    for (int c = 0; c < 16; ++c) {
        __syncthreads();                 // drains vmcnt: buf[c&1] ready; prev reads done
        if (c < 15) stage((c + 1) & 1, (c + 1) * 64);   // prefetch under this chunk's MFMAs
        const int bsel = c & 1;
#pragma unroll
        for (int ntt = 0; ntt < 2; ++ntt) {
            const int nt = grp * 2 + ntt;
            f32x4 c0a = {0.f, 0.f, 0.f, 0.f};
            f32x4 c1a = c0a, c2a = c0a, c0b = c0a, c1b = c0a, c2b = c0a;
#pragma unroll
            for (int ks = 0; ks < 8; ++ks) {
                const int off = ((nt * 8 + ks) * 64 + l) * 8;
                s16x8 ch = *(const s16x8*)&bh_lds[bsel][off];
                s16x8 cl = *(const s16x8*)&bl_lds[bsel][off];
                c0a = __builtin_amdgcn_mfma_f32_16x16x32_bf16(ch, xh[0][ks], c0a, 0, 0, 0);
                c0b = __builtin_amdgcn_mfma_f32_16x16x32_bf16(ch, xh[1][ks], c0b, 0, 0, 0);
                c1a = __builtin_amdgcn_mfma_f32_16x16x32_bf16(cl, xh[0][ks], c1a, 0, 0, 0);
                c1b = __builtin_amdgcn_mfma_f32_16x16x32_bf16(cl, xh[1][ks], c1b, 0, 0, 0);
                c2a = __builtin_amdgcn_mfma_f32_16x16x32_bf16(ch, xl[0][ks], c2a, 0, 0, 0);
                c2b = __builtin_amdgcn_mfma_f32_16x16x32_bf16(ch, xl[1][ks], c2b, 0, 0, 0);
            }
#pragma unroll
            for (int r = 0; r < 4; ++r) {
                const int code = c * 64 + nt * 16 + quad * 4 + r;
                const float e2v = e2_lds[code];
                float da = c0a[r] + c1a[r] + c2a[r];
                float db = c0b[r] + c1b[r] + c2b[r];
                ins4(e2v - 2.0f * da, code, tva, tia);
                ins4(e2v - 2.0f * db, code, tvb, tib);
            }
        }
    }

    // merge top-4 across the 4 quads holding the same x-row (lanes l, l^16, l^32)
#pragma unroll
    for (int st = 16; st <= 32; st <<= 1) {
        float ov[4]; int oi[4];
#pragma unroll
        for (int s = 0; s < 4; ++s) {
            ov[s] = __shfl_xor(tva[s], st, 64);
            oi[s] = __shfl_xor(tia[s], st, 64);
        }
#pragma unroll
        for (int s = 0; s < 4; ++s) ins4(ov[s], oi[s], tva, tia);
#pragma unroll
        for (int s = 0; s < 4; ++s) {
            ov[s] = __shfl_xor(tvb[s], st, 64);
            oi[s] = __shfl_xor(tib[s], st, 64);
        }
#pragma unroll
        for (int s = 0; s < 4; ++s) ins4(ov[s], oi[s], tvb, tib);
    }

    // merge the two code-groups (exact, order-independent lex top-4) via LDS
    // scratch carved from bh_lds[0]: buffer 0's last reads finished before the
    // c=15 barrier (c=15 uses buffer 1), so it is dead here.
    float* mv = (float*)&bh_lds[0][0];        // 128 slots x 4 floats
    int*   mi = (int*)&bh_lds[0][4096];       // 128 slots x 4 ints
    if (grp == 1 && quad == 0) {
        const int sa = p * 32 + c16;          // tile 0 slot
        const int sb = sa + 16;               // tile 1 slot
#pragma unroll
        for (int s = 0; s < 4; ++s) {
            mv[sa * 4 + s] = tva[s]; mi[sa * 4 + s] = tia[s];
            mv[sb * 4 + s] = tvb[s]; mi[sb * 4 + s] = tib[s];
        }
    }
    __syncthreads();
    if (grp == 0 && quad == 0) {
        const int sa = p * 32 + c16;
        const int sb = sa + 16;
#pragma unroll
        for (int s = 0; s < 4; ++s) ins4(mv[sa * 4 + s], mi[sa * 4 + s], tva, tia);
#pragma unroll
        for (int s = 0; s < 4; ++s) ins4(mv[sb * 4 + s], mi[sb * 4 + s], tvb, tib);
        const int ga = row0 + p * 32 + c16;   // tile 0 row
        const int gb = ga + 16;               // tile 1 row
#pragma unroll
        for (int s = 0; s < 4; ++s) {
            topv[ga * 4 + s] = tva[s]; topi[ga * 4 + s] = tia[s];
            topv[gb * 4 + s] = tvb[s]; topi[gb * 4 + s] = tib[s];
        }
    }
}

// ---------------------------------------------------------------------------
// Fused decide + gather: 64 rows/block. Threads 0..63 decide (fast path or
// exact fp32 rescore within DELTA — verbatim R2-proven logic), index passes
// through LDS, then all 256 threads do the coalesced float4 gather.
__global__ __launch_bounds__(256) void decide_gather_kernel(const float* __restrict__ X,
                                                            const float* __restrict__ E,
                                                            const float* __restrict__ e2g,
                                                            const float* __restrict__ x2g,
                                                            const float* __restrict__ topv,
                                                            const int* __restrict__ topi,
                                                            float* __restrict__ out0,
                                                            float* __restrict__ out1,
                                                            float* __restrict__ out2) {
    __shared__ int sidx[64];
    const int tid  = threadIdx.x;
    const int row0 = blockIdx.x * 64;
    if (tid < 64) {
        const int r = row0 + tid;
        float tv[4]; int ti[4];
#pragma unroll
        for (int s = 0; s < 4; ++s) { tv[s] = topv[r * 4 + s]; ti[s] = topi[r * 4 + s]; }

        int best = ti[0];
        if (!(tv[1] > tv[0] + DELTA)) {
            const float* xr = X + (size_t)r * DIM;
            const float x2v = x2g[r];
            float bq = INFINITY; int bi = 0x7fffffff;
            for (int cnd = 0; cnd < 4; ++cnd) {
                if (tv[cnd] <= tv[0] + DELTA) {
                    const int k = ti[cnd];
                    const float* er = E + (size_t)k * DIM;
                    float dot = 0.f;
                    for (int d = 0; d < DIM; d += 4) {   // sequential fp32 chain (BLAS order)
                        float4 xv = *(const float4*)(xr + d);
                        float4 ev = *(const float4*)(er + d);
                        dot = fmaf(xv.x, ev.x, dot);
                        dot = fmaf(xv.y, ev.y, dot);
                        dot = fmaf(xv.z, ev.z, dot);
                        dot = fmaf(xv.w, ev.w, dot);
                    }
                    float t1 = e2g[k] - 2.0f * dot;   // numpy elementwise rounding
                    float q  = t1 + x2v;
                    if (q < bq || (q == bq && k < bi)) { bq = q; bi = k; }
                }
            }
            best = bi;
        }
        sidx[tid] = best;
        out2[r] = (float)best;
    }
    __syncthreads();
#pragma unroll
    for (int it = 0; it < 16; ++it) {
        int f = tid + it * 256;
        int rr = f >> 6;
        int pp = f & 63;
        int ix = sidx[rr];
        float4 v = *(const float4*)(E + (size_t)ix * DIM + pp * 4);
        size_t o = (size_t)(row0 + rr) * DIM + (size_t)pp * 4;
        *(float4*)(out0 + o) = v;
        *(float4*)(out1 + o) = v;
    }
}

// ---------------------------------------------------------------------------
extern "C" void kernel_launch(void* const* d_in, const int* in_sizes, int n_in,
                              void* d_out, int out_size, void* d_ws, size_t ws_size,
                              hipStream_t stream) {
    const float* X = (const float*)d_in[0];
    const float* E = (const float*)d_in[1];

    // ws layout (all 16B-aligned): ~2.4 MB total
    float* e2 = (float*)d_ws;                              // 1024 f
    float* x2 = e2 + KCODES;                               // 32768 f
    unsigned short* Eh = (unsigned short*)(x2 + N_ROWS);   // 262144 us
    unsigned short* El = Eh + KCODES * DIM;                // 262144 us
    float* topv = (float*)(El + KCODES * DIM);             // 131072 f
    int*   topi = (int*)(topv + N_ROWS * 4);               // 131072 i

    float* out0 = (float*)d_out;
    float* out1 = out0 + (size_t)N_ROWS * DIM;
    float* out2 = out1 + (size_t)N_ROWS * DIM;

    prep_kernel<<<dim3(KCODES / 4 + N_ROWS / 4), dim3(256), 0, stream>>>(E, X, e2, x2,
                                                                         Eh, El);
    vq_mfma_kernel<<<dim3(N_ROWS / 128), dim3(512), 0, stream>>>(X, Eh, El, e2,
                                                                 topv, topi);
    decide_gather_kernel<<<dim3(N_ROWS / 64), dim3(256), 0, stream>>>(X, E, e2, x2,
                                                                      topv, topi,
                                                                      out0, out1, out2);
}

// Round 3
// 201.730 us; speedup vs baseline: 1.3657x; 1.1563x over previous
//
#include <hip/hip_runtime.h>
#include <math.h>

// Problem constants (fixed by reference: B=32,T=1024,D=256,K=1024)
#define N_ROWS 32768
#define DIM    256
#define KCODES 1024
// Screen is single-pass bf16 (s~ = e2 - 2*xh.eh). Score error: sigma ~2.8e-5,
// max over 3.4e7 samples ~1.5e-4; plus numpy fp32 rounding band ~6e-5.
// DELTA = 5e-4 covers flips at >10 sigma; ambiguous rows get exact fp32
// rescore (R2-proven numpy-rounding path). Rescue rate ~7% of rows.
#define DELTA  5.0e-4f

typedef float f32x4 __attribute__((ext_vector_type(4)));
typedef short s16x8 __attribute__((ext_vector_type(8)));

__device__ inline unsigned short bf_rne(float f) {
    unsigned u = __float_as_uint(f);
    return (unsigned short)((u + 0x7FFFu + ((u >> 16) & 1u)) >> 16);
}

// lex insert (v,ix) into ascending top-4 (ties -> lower index first)
__device__ inline void ins4(float v, int ix, float (&tv)[4], int (&ti)[4]) {
    if (v < tv[3] || (v == tv[3] && ix < ti[3])) {
        if (v < tv[2] || (v == tv[2] && ix < ti[2])) {
            tv[3] = tv[2]; ti[3] = ti[2];
            if (v < tv[1] || (v == tv[1] && ix < ti[1])) {
                tv[2] = tv[1]; ti[2] = ti[1];
                if (v < tv[0] || (v == tv[0] && ix < ti[0])) {
                    tv[1] = tv[0]; ti[1] = ti[0]; tv[0] = v; ti[0] = ix;
                } else { tv[1] = v; ti[1] = ix; }
            } else { tv[2] = v; ti[2] = ix; }
        } else { tv[3] = v; ti[3] = ix; }
    }
}

// async global->LDS, 16B per lane. LDS dest = wave-uniform base + lane*16 (HW rule).
__device__ __forceinline__ void gl_lds16(const void* gp, void* lp) {
    __builtin_amdgcn_global_load_lds(
        (__attribute__((address_space(1))) void*)(void*)gp,
        (__attribute__((address_space(3))) void*)lp, 16, 0, 0);
}

// ---------------------------------------------------------------------------
// Fused prep: blocks [0,256) do E prep (e2 pairwise + bf16 hi of E);
// blocks [256, 256+8192) do X row sum-of-squares. Both reductions are verbatim
// copies of the R2-proven numpy-pairwise kernels.
__global__ __launch_bounds__(256) void prep_kernel(const float* __restrict__ E,
                                                   const float* __restrict__ X,
                                                   float* __restrict__ e2,
                                                   float* __restrict__ x2,
                                                   unsigned short* __restrict__ Eh) {
    __shared__ float sq[4][260];
    const int wave = threadIdx.x >> 6;
    const int lane = threadIdx.x & 63;
    if (blockIdx.x < KCODES / 4) {
        const int row = blockIdx.x * 4 + wave;
        const float4* rp = (const float4*)(E + (size_t)row * DIM);
        float4 v = rp[lane];
        sq[wave][lane * 4 + 0] = v.x * v.x;
        sq[wave][lane * 4 + 1] = v.y * v.y;
        sq[wave][lane * 4 + 2] = v.z * v.z;
        sq[wave][lane * 4 + 3] = v.w * v.w;
        float fs[4] = {v.x, v.y, v.z, v.w};
        ushort4 hv;
        unsigned short* hp = (unsigned short*)&hv;
#pragma unroll
        for (int j = 0; j < 4; ++j) hp[j] = bf_rne(fs[j]);
        *(ushort4*)(Eh + (size_t)row * DIM + lane * 4) = hv;
        if (lane < 8) {
#pragma clang fp contract(off)
            const int j = lane;
            float rA = sq[wave][j];
#pragma unroll
            for (int m = 1; m < 16; ++m) rA += sq[wave][8 * m + j];
            float rB = sq[wave][128 + j];
#pragma unroll
            for (int m = 1; m < 16; ++m) rB += sq[wave][128 + 8 * m + j];
            rA = rA + __shfl_xor(rA, 1, 64); rA = rA + __shfl_xor(rA, 2, 64);
            rA = rA + __shfl_xor(rA, 4, 64);
            rB = rB + __shfl_xor(rB, 1, 64); rB = rB + __shfl_xor(rB, 2, 64);
            rB = rB + __shfl_xor(rB, 4, 64);
            if (j == 0) e2[row] = rA + rB;
        }
    } else {
        const int row = (blockIdx.x - KCODES / 4) * 4 + wave;
        if (row >= N_ROWS) return;
        const float4* rp = (const float4*)(X + (size_t)row * DIM);
        float4 v = rp[lane];
        sq[wave][lane * 4 + 0] = v.x * v.x;
        sq[wave][lane * 4 + 1] = v.y * v.y;
        sq[wave][lane * 4 + 2] = v.z * v.z;
        sq[wave][lane * 4 + 3] = v.w * v.w;
        if (lane < 8) {
#pragma clang fp contract(off)
            const int j = lane;
            float rA = sq[wave][j];
#pragma unroll
            for (int m = 1; m < 16; ++m) rA += sq[wave][8 * m + j];
            float rB = sq[wave][128 + j];
#pragma unroll
            for (int m = 1; m < 16; ++m) rB += sq[wave][128 + 8 * m + j];
            rA = rA + __shfl_xor(rA, 1, 64); rA = rA + __shfl_xor(rA, 2, 64);
            rA = rA + __shfl_xor(rA, 4, 64);
            rB = rB + __shfl_xor(rB, 1, 64); rB = rB + __shfl_xor(rB, 2, 64);
            rB = rB + __shfl_xor(rB, 4, 64);
            if (j == 0) x2[row] = rA + rB;
        }
    }
}

// ---------------------------------------------------------------------------
// Fused screen + decide + gather. 512 threads = 8 waves, 64 rows/block,
// grid 512 -> 2 blocks/CU (LDS ~68 KB), 4 waves/SIMD at <=128 VGPR (xh is
// 64 VGPRs now; round-2's 29 MB scratch spill eliminated).
// Wave w: row-pair p=w&1 (rows p*32..p*32+31, 2 tiles of 16), code quarter
// grp=w>>1 (nt=grp of each staged 64-code chunk). Per ks: 1 ds_read_b128
// feeds 2 MFMAs (32 FLOP/LDS-byte). Staging: async global_load_lds,
// double-buffered, one barrier per chunk (round-1/2 proven pattern).
// Epilogue: exact quad/grp top-4 merge, in-kernel decide (fast path or exact
// fp32 numpy-rounded rescore, verbatim R2 logic), LDS idx pass, gather.
__global__ __launch_bounds__(512, 4) void vq_fused_kernel(const float* __restrict__ X,
                                                          const unsigned short* __restrict__ Eh,
                                                          const float* __restrict__ e2g,
                                                          const float* __restrict__ x2g,
                                                          const float* __restrict__ E,
                                                          float* __restrict__ out0,
                                                          float* __restrict__ out1,
                                                          float* __restrict__ out2) {
    __shared__ __align__(16) short bh_lds[2][16384];  // 2 x 32 KB code chunks
    __shared__ float e2_lds[KCODES];                  // 4 KB
    __shared__ int sidx[64];

    const int tid  = threadIdx.x;
    const int w    = tid >> 6;
    const int l    = tid & 63;
    const int c16  = l & 15;
    const int quad = l >> 4;
    const int p    = w & 1;    // row-pair (rows p*32 .. p*32+31)
    const int grp  = w >> 1;   // code quarter: nt = grp
    const int row0 = blockIdx.x * 64;

    // e2 -> LDS once (drained by first barrier)
    if (tid < 256) *(float4*)&e2_lds[tid * 4] = *(const float4*)&e2g[tid * 4];

    // ---- X fragments (B-operand): 2 tiles x 16 rows, hi only, K=256 ----
    s16x8 xh[2][8];
#pragma unroll
    for (int t = 0; t < 2; ++t) {
        const float* xrow = X + (size_t)(row0 + p * 32 + t * 16 + c16) * DIM + quad * 8;
#pragma unroll
        for (int ks = 0; ks < 8; ++ks) {
            float4 f0 = *(const float4*)(xrow + ks * 32);
            float4 f1 = *(const float4*)(xrow + ks * 32 + 4);
            float fs[8] = {f0.x, f0.y, f0.z, f0.w, f1.x, f1.y, f1.z, f1.w};
#pragma unroll
            for (int j = 0; j < 8; ++j) xh[t][ks][j] = (short)bf_rne(fs[j]);
        }
    }

    float tva[4], tvb[4];
    int   tia[4], tib[4];
#pragma unroll
    for (int s = 0; s < 4; ++s) {
        tva[s] = INFINITY; tvb[s] = INFINITY;
        tia[s] = 0x7fffffff; tib[s] = 0x7fffffff;
    }

    // stage codes [cb, cb+64): 32 granules of 1KB; 8 waves x 4 each
    auto stage = [&](int bsel, int cb) {
        const unsigned short* Ehc = Eh + (size_t)cb * DIM;
#pragma unroll
        for (int gg = 0; gg < 4; ++gg) {
            const int g  = w + gg * 8;              // wave-uniform, 0..31
            const int nt = g >> 3, ks = g & 7;
            const size_t eo = (size_t)(nt * 16 + c16) * DIM + ks * 32 + quad * 8;
            gl_lds16(Ehc + eo, &bh_lds[bsel][g * 512]);
        }
    };

    stage(0, 0);

    for (int c = 0; c < 16; ++c) {
        __syncthreads();                 // buf[c&1] staged; prev chunk's reads done
        if (c < 15) stage((c + 1) & 1, (c + 1) * 64);   // prefetch under MFMAs
        const int bsel = c & 1;
        const int nt   = grp;
        f32x4 c0a = {0.f, 0.f, 0.f, 0.f};
        f32x4 c0b = c0a;
#pragma unroll
        for (int ks = 0; ks < 8; ++ks) {
            s16x8 ch = *(const s16x8*)&bh_lds[bsel][((nt * 8 + ks) * 64 + l) * 8];
            c0a = __builtin_amdgcn_mfma_f32_16x16x32_bf16(ch, xh[0][ks], c0a, 0, 0, 0);
            c0b = __builtin_amdgcn_mfma_f32_16x16x32_bf16(ch, xh[1][ks], c0b, 0, 0, 0);
        }
        f32x4 e2v = *(const f32x4*)&e2_lds[c * 64 + nt * 16 + quad * 4];
#pragma unroll
        for (int r = 0; r < 4; ++r) {
            const int code = c * 64 + nt * 16 + quad * 4 + r;
            ins4(fmaf(-2.0f, c0a[r], e2v[r]), code, tva, tia);
            ins4(fmaf(-2.0f, c0b[r], e2v[r]), code, tvb, tib);
        }
    }

    // merge top-4 across the 4 quads holding the same x-row (lanes l^16, l^32)
#pragma unroll
    for (int st = 16; st <= 32; st <<= 1) {
        float ov[4]; int oi[4];
#pragma unroll
        for (int s = 0; s < 4; ++s) {
            ov[s] = __shfl_xor(tva[s], st, 64);
            oi[s] = __shfl_xor(tia[s], st, 64);
        }
#pragma unroll
        for (int s = 0; s < 4; ++s) ins4(ov[s], oi[s], tva, tia);
#pragma unroll
        for (int s = 0; s < 4; ++s) {
            ov[s] = __shfl_xor(tvb[s], st, 64);
            oi[s] = __shfl_xor(tib[s], st, 64);
        }
#pragma unroll
        for (int s = 0; s < 4; ++s) ins4(ov[s], oi[s], tvb, tib);
    }

    // merge the 4 code-quarters (exact, order-independent lex top-4) via LDS
    // scratch carved from bh_lds[0] (dead: chunk 15 reads buf1; buf0 last
    // written by chunk-13's prefetch, last read in chunk 14).
    float* mv = (float*)&bh_lds[0][0];        // 192 slots x 4 floats (3 KB)
    int*   mi = (int*)&bh_lds[0][8192];       // 192 slots x 4 ints   (3 KB)
    if (grp >= 1 && quad == 0) {
        const int sa = (grp - 1) * 64 + p * 32 + c16;   // tile 0 slot
        const int sb = sa + 16;                          // tile 1 slot
#pragma unroll
        for (int s = 0; s < 4; ++s) {
            mv[sa * 4 + s] = tva[s]; mi[sa * 4 + s] = tia[s];
            mv[sb * 4 + s] = tvb[s]; mi[sb * 4 + s] = tib[s];
        }
    }
    __syncthreads();
    if (grp == 0 && quad == 0) {
#pragma unroll
        for (int g2 = 1; g2 < 4; ++g2) {
            const int sa = (g2 - 1) * 64 + p * 32 + c16;
            const int sb = sa + 16;
#pragma unroll
            for (int s = 0; s < 4; ++s) ins4(mv[sa * 4 + s], mi[sa * 4 + s], tva, tia);
#pragma unroll
            for (int s = 0; s < 4; ++s) ins4(mv[sb * 4 + s], mi[sb * 4 + s], tvb, tib);
        }
        // ---- decide both rows (verbatim R2-proven logic) ----
#pragma unroll
        for (int t = 0; t < 2; ++t) {
            float* tv = t ? tvb : tva;
            int*   ti = t ? tib : tia;
            const int r = row0 + p * 32 + t * 16 + c16;
            int best = ti[0];
            if (!(tv[1] > tv[0] + DELTA)) {
                const float* xr = X + (size_t)r * DIM;
                const float x2v = x2g[r];
                float bq = INFINITY; int bi = 0x7fffffff;
                for (int cnd = 0; cnd < 4; ++cnd) {
                    if (tv[cnd] <= tv[0] + DELTA) {
                        const int k = ti[cnd];
                        const float* er = E + (size_t)k * DIM;
                        float dot = 0.f;
                        for (int d = 0; d < DIM; d += 4) {   // sequential fp32 chain
                            float4 xv = *(const float4*)(xr + d);
                            float4 ev = *(const float4*)(er + d);
                            dot = fmaf(xv.x, ev.x, dot);
                            dot = fmaf(xv.y, ev.y, dot);
                            dot = fmaf(xv.z, ev.z, dot);
                            dot = fmaf(xv.w, ev.w, dot);
                        }
                        float t1 = e2_lds[k] - 2.0f * dot;   // numpy elementwise rounding
                        float q  = t1 + x2v;
                        if (q < bq || (q == bq && k < bi)) { bq = q; bi = k; }
                    }
                }
                best = bi;
            }
            sidx[p * 32 + t * 16 + c16] = best;
            out2[r] = (float)best;
        }
    }
    __syncthreads();

    // ---- gather epilogue: 64 rows, coalesced float4 writes ----
#pragma unroll
    for (int it = 0; it < 8; ++it) {
        int f = tid + it * 512;
        int rr = f >> 6;
        int pp = f & 63;
        int ix = sidx[rr];
        float4 v = *(const float4*)(E + (size_t)ix * DIM + pp * 4);
        size_t o = (size_t)(row0 + rr) * DIM + (size_t)pp * 4;
        *(float4*)(out0 + o) = v;
        *(float4*)(out1 + o) = v;
    }
}

// ---------------------------------------------------------------------------
extern "C" void kernel_launch(void* const* d_in, const int* in_sizes, int n_in,
                              void* d_out, int out_size, void* d_ws, size_t ws_size,
                              hipStream_t stream) {
    const float* X = (const float*)d_in[0];
    const float* E = (const float*)d_in[1];

    // ws layout (all 16B-aligned): ~0.65 MB total
    float* e2 = (float*)d_ws;                              // 1024 f
    float* x2 = e2 + KCODES;                               // 32768 f
    unsigned short* Eh = (unsigned short*)(x2 + N_ROWS);   // 262144 us

    float* out0 = (float*)d_out;
    float* out1 = out0 + (size_t)N_ROWS * DIM;
    float* out2 = out1 + (size_t)N_ROWS * DIM;

    prep_kernel<<<dim3(KCODES / 4 + N_ROWS / 4), dim3(256), 0, stream>>>(E, X, e2, x2, Eh);
    vq_fused_kernel<<<dim3(N_ROWS / 64), dim3(512), 0, stream>>>(X, Eh, e2, x2, E,
                                                                 out0, out1, out2);
}